// Round 1
// baseline (261.918 us; speedup 1.0000x reference)
//
#include <hip/hip_runtime.h>

#define B   64
#define K   512
#define C   4
#define NL  5
#define NCH 16          // j-chunks for the transposed matvec partials
#define BK  (B*K)

typedef _Float16 half_t;
typedef _Float16 half8 __attribute__((ext_vector_type(8)));

// ---------------------------------------------------------------------------
// Precompute: Habs2 = h_re^2 + h_im^2 as fp16 (33.5 MB, L3-resident), plus
// dabs2[b,k] = |H[b,k,k]|^2 extracted on the fly.
// ---------------------------------------------------------------------------
__global__ __launch_bounds__(256) void k_pre(const float* __restrict__ hre,
                                             const float* __restrict__ him,
                                             half_t* __restrict__ habs,
                                             float* __restrict__ dabs2) {
    size_t t    = (size_t)blockIdx.x * blockDim.x + threadIdx.x;
    size_t base = t * 8;                       // 8 elements per thread
    const float4* r4 = (const float4*)(hre + base);
    const float4* i4 = (const float4*)(him + base);
    float4 r0 = r4[0], r1 = r4[1];
    float4 i0 = i4[0], i1 = i4[1];
    float re[8] = {r0.x, r0.y, r0.z, r0.w, r1.x, r1.y, r1.z, r1.w};
    float im[8] = {i0.x, i0.y, i0.z, i0.w, i1.x, i1.y, i1.z, i1.w};
    float s[8];
    half8 h;
#pragma unroll
    for (int q = 0; q < 8; ++q) {
        s[q] = re[q] * re[q] + im[q] * im[q];
        h[q] = (_Float16)s[q];
    }
    *(half8*)(habs + base) = h;
#pragma unroll
    for (int q = 0; q < 8; ++q) {
        size_t e  = base + q;
        int   col = (int)(e & (K - 1));
        int   row = (int)((e >> 9) & (K - 1));
        if (row == col) {
            size_t b     = e >> 18;            // / (K*K)
            dabs2[b * K + row] = s[q];
        }
    }
}

// ---------------------------------------------------------------------------
// Init: v state (float2) and xsq = |v|^2
// ---------------------------------------------------------------------------
__global__ __launch_bounds__(256) void k_init(const float* __restrict__ vre,
                                              const float* __restrict__ vim,
                                              float2* __restrict__ vstate,
                                              float* __restrict__ xsq) {
    int t = blockIdx.x * blockDim.x + threadIdx.x;
    float a = vre[t], b = vim[t];
    vstate[t] = make_float2(a, b);
    xsq[t]    = a * a + b * b;
}

// ---------------------------------------------------------------------------
// K1: cov[b,j] = Habs2[b,j,:] . xsq[b,:] + noise, then per-row elementwise:
//   A = |d|^2 * xsq_j ; w = cov/(cov - A) (real!) ; s = |d|^2 * w / cov
//   vtilde = s * v ; ulvec = A * w / cov^2
// One wave per row (8 rows per wave), lane covers 8 consecutive fp16 columns.
// Grid: B * (K/32) = 1024 blocks of 256.
// ---------------------------------------------------------------------------
__global__ __launch_bounds__(256) void k_cov(const half_t* __restrict__ habs,
                                             const float* __restrict__ xsq,
                                             const float* __restrict__ noise,
                                             const float* __restrict__ dabs2,
                                             const float2* __restrict__ vstate,
                                             float* __restrict__ ulvec,
                                             float2* __restrict__ vtilde) {
    int lane = threadIdx.x & 63;
    int wv   = threadIdx.x >> 6;
    int b    = blockIdx.x >> 4;       // 16 row-blocks per batch
    int rblk = blockIdx.x & 15;

    const float4* x4 = (const float4*)(xsq + b * K);
    float4 xa = x4[lane * 2];
    float4 xb = x4[lane * 2 + 1];

    for (int r = 0; r < 8; ++r) {
        int j = rblk * 32 + wv * 8 + r;
        const half8* rp = (const half8*)(habs + ((size_t)b * K + j) * K);
        half8 h = rp[lane];
        float acc = (float)h[0] * xa.x + (float)h[1] * xa.y +
                    (float)h[2] * xa.z + (float)h[3] * xa.w +
                    (float)h[4] * xb.x + (float)h[5] * xb.y +
                    (float)h[6] * xb.z + (float)h[7] * xb.w;
#pragma unroll
        for (int off = 32; off; off >>= 1) acc += __shfl_xor(acc, off, 64);
        if (lane == 0) {
            int bj   = b * K + j;
            float cov = acc + noise[bj];
            float A   = dabs2[bj] * xsq[bj];
            float w   = cov / (cov - A);
            float s   = dabs2[bj] * w / cov;
            float2 vv = vstate[bj];
            vtilde[bj] = make_float2(s * vv.x, s * vv.y);
            ulvec[bj]  = A * w / (cov * cov);
        }
    }
}

// ---------------------------------------------------------------------------
// K2: transposed matvec partials: ulpart[jc][b][k] = sum_{j in chunk jc}
//     Habs2[b,j,k] * ulvec[b,j].  Wave handles (b, jc); lane owns 8
//     consecutive columns; fully coalesced fp16x8 loads. No atomics.
// Grid: B*NCH/4 = 256 blocks of 256.
// ---------------------------------------------------------------------------
__global__ __launch_bounds__(256) void k_tmv(const half_t* __restrict__ habs,
                                             const float* __restrict__ ulvec,
                                             float* __restrict__ ulpart) {
    int lane = threadIdx.x & 63;
    int wv   = threadIdx.x >> 6;
    int task = blockIdx.x * 4 + wv;   // B*NCH tasks
    int b    = task >> 4;             // / NCH
    int jc   = task & (NCH - 1);

    float acc[8] = {0.f, 0.f, 0.f, 0.f, 0.f, 0.f, 0.f, 0.f};
    const half8* base = (const half8*)(habs + ((size_t)b * K + jc * 32) * K);
    const float* ulv  = ulvec + b * K + jc * 32;
    for (int jj = 0; jj < 32; ++jj) {
        half8 h  = base[jj * (K / 8) + lane];
        float ul = ulv[jj];                    // wave-uniform, HW broadcast
#pragma unroll
        for (int q = 0; q < 8; ++q) acc[q] += (float)h[q] * ul;
    }
    float* outp = ulpart + ((size_t)jc * B + b) * K + lane * 8;
    ((float4*)outp)[0] = make_float4(acc[0], acc[1], acc[2], acc[3]);
    ((float4*)outp)[1] = make_float4(acc[4], acc[5], acc[6], acc[7]);
}

// ---------------------------------------------------------------------------
// K3: finish — sum partials, mu/ula, ar/dl mix, CReLU, rc recombine, power
// correction; write new v state, xsq, and this layer's output slice.
// Grid: BK/256 = 128 blocks.
// ---------------------------------------------------------------------------
__global__ __launch_bounds__(256) void k_fin(const float* __restrict__ ulpart,
                                             const float2* __restrict__ vtilde,
                                             const float* __restrict__ maxpow,
                                             const float* __restrict__ ar_re,
                                             const float* __restrict__ ar_im,
                                             const float* __restrict__ dl_re,
                                             const float* __restrict__ dl_im,
                                             const float* __restrict__ rc_re,
                                             const float* __restrict__ rc_im,
                                             float2* __restrict__ vstate,
                                             float* __restrict__ xsq,
                                             float* __restrict__ out) {
    int t = blockIdx.x * blockDim.x + threadIdx.x;
    float ul = 0.f;
#pragma unroll
    for (int jc = 0; jc < NCH; ++jc) ul += ulpart[jc * BK + t];

    float2 vt = vtilde[t];
    float  p  = maxpow[t];
    float avt = sqrtf(vt.x * vt.x + vt.y * vt.y);
    float mu  = fmaxf(avt / sqrtf(p) - ul, 0.f);
    float ula = ul + mu;
    float inv = 1.f / ula;

    float ax = 0.f, ay = 0.f;
#pragma unroll
    for (int c = 0; c < C; ++c) {
        float gre = ar_re[c] * inv + dl_re[c];
        float gim = ar_im[c] * inv + dl_im[c];
        float zre = vt.x * gre - vt.y * gim;   // vt * g
        float zim = vt.x * gim + vt.y * gre;
        zre = fmaxf(zre, 0.f);                 // CReLU
        zim = fmaxf(zim, 0.f);
        ax += zre * rc_re[c] - zim * rc_im[c]; // += z * rc
        ay += zre * rc_im[c] + zim * rc_re[c];
    }
    float n2   = ax * ax + ay * ay;
    float cur  = fmaxf(p, n2);
    float corr = fminf(sqrtf(p / cur), 1.f);
    ax *= corr;
    ay *= corr;
    vstate[t] = make_float2(ax, ay);
    xsq[t]    = ax * ax + ay * ay;
    out[2 * t]     = ax;
    out[2 * t + 1] = ay;
}

// ---------------------------------------------------------------------------
extern "C" void kernel_launch(void* const* d_in, const int* in_sizes, int n_in,
                              void* d_out, int out_size, void* d_ws, size_t ws_size,
                              hipStream_t stream) {
    const float* hre   = (const float*)d_in[0];
    const float* him   = (const float*)d_in[1];
    const float* noise = (const float*)d_in[2];
    const float* mp    = (const float*)d_in[3];
    const float* vre   = (const float*)d_in[4];
    const float* vim   = (const float*)d_in[5];
    const float* ar_re = (const float*)d_in[6];
    const float* ar_im = (const float*)d_in[7];
    const float* dl_re = (const float*)d_in[8];
    const float* dl_im = (const float*)d_in[9];
    const float* rc_re = (const float*)d_in[10];
    const float* rc_im = (const float*)d_in[11];
    float* out = (float*)d_out;

    char*   ws     = (char*)d_ws;
    size_t  off    = 0;
    half_t* habs   = (half_t*)(ws + off); off += (size_t)BK * K * 2;  // 33.5 MB
    float*  dabs2  = (float*) (ws + off); off += (size_t)BK * 4;
    float2* vstate = (float2*)(ws + off); off += (size_t)BK * 8;
    float*  xsq    = (float*) (ws + off); off += (size_t)BK * 4;
    float*  ulvec  = (float*) (ws + off); off += (size_t)BK * 4;
    float2* vtilde = (float2*)(ws + off); off += (size_t)BK * 8;
    float*  ulpart = (float*) (ws + off); off += (size_t)NCH * BK * 4;

    k_pre <<<(size_t)BK * K / 8 / 256, 256, 0, stream>>>(hre, him, habs, dabs2);
    k_init<<<BK / 256, 256, 0, stream>>>(vre, vim, vstate, xsq);

    for (int l = 0; l < NL; ++l) {
        k_cov<<<B * 16, 256, 0, stream>>>(habs, xsq, noise, dabs2, vstate,
                                          ulvec, vtilde);
        k_tmv<<<B * NCH / 4, 256, 0, stream>>>(habs, ulvec, ulpart);
        k_fin<<<BK / 256, 256, 0, stream>>>(ulpart, vtilde, mp,
                                            ar_re, ar_im, dl_re, dl_im,
                                            rc_re, rc_im,
                                            vstate, xsq,
                                            out + (size_t)l * BK * 2);
    }
}